// Round 3
// baseline (186.538 us; speedup 1.0000x reference)
//
#include <hip/hip_runtime.h>
#include <math.h>

// v9: 24 waves/CU (6.4KB LDS/wave) + rolling row cache + static ds offsets.
//
// Evidence: v6 and v8 both ~47us kernel at 12 waves/CU (LDS-capped: v6
// 51.2KB/4-wave block, v8 12.8KB/1-wave block -- same 12 waves/CU).
// Chip-wide VALU issue is invariant ~26us (v6 41%x66, v7 39%x65.6) ->
// kernel is stall-bound at ~55% VALU duty; occupancy is the lever.
// Changes vs v8:
//  (1) 16 samples/wave (6.4KB), 2-wave blocks (12.8KB) -> 12 blocks/CU
//      = 24 waves/CU, 2x all prior versions; 16384 waves of work.
//      No intra-wave pipeline (TLP hides the one cold stage wait).
//  (2) rolling row cache: r2(i)==r0(i+1) carried in rotating X[2][10]
//      -> 55 ds_read_b64/batch (was 75); all row reads use 2 base regs
//      (myq, mx) + compile-time offsets -> no per-i address VALU/cndmask.
//  (3) stage issued before weight setup (s_loads overlap VMEM flight).

typedef float v2f __attribute__((ext_vector_type(2)));

#define SREAD(x) __int_as_float(__builtin_amdgcn_readfirstlane(__float_as_int(x)))
#define WAITVM(N) asm volatile("s_waitcnt vmcnt(" #N ")" ::: "memory")

__device__ __forceinline__ float dpp_swap1_f(float x) {      // lane ^ 1
    return __int_as_float(__builtin_amdgcn_mov_dpp(__float_as_int(x), 0xB1, 0xF, 0xF, true));
}
__device__ __forceinline__ float dpp_swap2_f(float x) {      // lane ^ 2
    return __int_as_float(__builtin_amdgcn_mov_dpp(__float_as_int(x), 0x4E, 0xF, 0xF, true));
}
__device__ __forceinline__ unsigned dpp_swap1_u(unsigned x) {
    return (unsigned)__builtin_amdgcn_mov_dpp((int)x, 0xB1, 0xF, 0xF, true);
}
__device__ __forceinline__ unsigned dpp_swap2_u(unsigned x) {
    return (unsigned)__builtin_amdgcn_mov_dpp((int)x, 0x4E, 0xF, 0xF, true);
}

__device__ __forceinline__ void gload16(const float* g, float* l) {
    __builtin_amdgcn_global_load_lds(
        (const __attribute__((address_space(1))) void*)g,
        (__attribute__((address_space(3))) void*)l, 16, 0, 0);
}
__device__ __forceinline__ void gload4(const float* g, float* l) {
    __builtin_amdgcn_global_load_lds(
        (const __attribute__((address_space(1))) void*)g,
        (__attribute__((address_space(3))) void*)l, 4, 0, 0);
}

__global__ __launch_bounds__(128, 6) void CNN2D_37495064494620_kernel(
    const float* __restrict__ v,
    const float* __restrict__ cw,   // [4,1,3,3]
    const float* __restrict__ cb,   // [4]
    const float* __restrict__ dw,   // [4,1,2,2]
    const float* __restrict__ db,   // [1]
    float* __restrict__ out,        // [2*B]
    int B)
{
    const int lane = threadIdx.x & 63;
    const int w    = threadIdx.x >> 6;    // wave in block (0..1)
    const int q    = lane & 1;            // conv-row parity
    const int h    = (lane >> 1) & 1;     // filter-pair owner (f0,f1 | f2,f3)
    const int g    = lane >> 2;           // sample within wave (0..15)

    __shared__ __align__(16) float smraw[3200];   // 2 waves x 16 samples x 100
    float* sm = smraw + w * 1600;

    // ---- stage FIRST: this wave's 16 samples (6400B = 6x1024B + 256B) ----
    const float* gb = v + (size_t)(blockIdx.x * 2 + w) * 1600;
    #pragma unroll
    for (int k = 0; k < 6; ++k)
        gload16(gb + k * 256 + lane * 4, sm + k * 256);
    gload4(gb + 1536 + lane, sm + 1536);

    // ---- uniform weights -> SGPRs (s_loads overlap the VMEM flight) ----
    float Wf[4][9];
    #pragma unroll
    for (int f = 0; f < 4; ++f)
        #pragma unroll
        for (int t = 0; t < 9; ++t)
            Wf[f][t] = SREAD(cw[f * 9 + t]);
    v2f Wsel[9];
    #pragma unroll
    for (int t = 0; t < 9; ++t)
        Wsel[t] = (v2f){ h ? Wf[2][t] : Wf[0][t], h ? Wf[3][t] : Wf[1][t] };
    const float cb0 = SREAD(cb[0]), cb1 = SREAD(cb[1]);
    const float cb2 = SREAD(cb[2]), cb3 = SREAD(cb[3]);
    const v2f Cbsel = (v2f){ h ? cb2 : cb0, h ? cb3 : cb1 };

    float Dw4[4][4];
    #pragma unroll
    for (int f = 0; f < 4; ++f)
        #pragma unroll
        for (int t = 0; t < 4; ++t)
            Dw4[f][t] = SREAD(dw[f * 4 + t]);
    const float Db = SREAD(db[0]);
    float Dkl[4];                         // this lane's tap kl = 2q+h
    #pragma unroll
    for (int f = 0; f < 4; ++f) {
        const float e01 = h ? Dw4[f][1] : Dw4[f][0];
        const float e23 = h ? Dw4[f][3] : Dw4[f][2];
        Dkl[f] = q ? e23 : e01;
    }
    const float Ds0 = h ? Dkl[2] : Dkl[0];   // own filter pair first
    const float Ds1 = h ? Dkl[3] : Dkl[1];
    const float Ds2 = h ? Dkl[0] : Dkl[2];
    const float Ds3 = h ? Dkl[1] : Dkl[3];

    WAITVM(0);   // this wave's 7 staging loads landed

    // Row bases: all reads below are static offsets from these two regs.
    const float* my  = sm + g * 100;
    const float* myq = my + q * 10;          // row (0+q): center rows = myq+20i
    const float* mx  = my + (q ? 0 : 90);    // wrap row: r0(0) and rowC(i=4)

    auto load5 = [&](float* dst, const float* src) {
        #pragma unroll
        for (int t = 0; t < 5; ++t) {
            float2 x = *(const float2*)(src + 2 * t);
            dst[2 * t] = x.x; dst[2 * t + 1] = x.y;
        }
    };

    unsigned sb = 0u;       // XOR of z sign bits (this lane's 25 taps)
    float l2 = 0.0f;        // sum of log2|z|
    float zpend = 0.0f;     // pending z for log-pairing

    float X[2][10];         // rotating parity-(1-q) rows: X[i&1]=r0(i)
    float RB[10];           // center row r1(i)
    load5(X[0], mx);        // r0(0)

    #pragma unroll
    for (int i = 0; i < 5; ++i) {
        load5(RB, myq + 20 * i);                              // r1 = 2i+q
        load5(X[(i + 1) & 1], (i == 4) ? mx : (myq + 10 + 20 * i));  // r2
        const float* R0 = X[i & 1];
        const float* R1 = RB;
        const float* R2 = X[(i + 1) & 1];

        #pragma unroll
        for (int j = 0; j < 5; ++j) {
            v2f a0 = Cbsel, a1 = Cbsel;     // cols 2j, 2j+1; this lane's 2 filters
            #pragma unroll
            for (int kc = 0; kc < 3; ++kc) {
                const int cc0 = (2 * j + kc + 9) % 10;        // compile-time
                const int cc1 = (2 * j + 1 + kc + 9) % 10;
                {
                    const v2f x0 = (v2f){R0[cc0], R0[cc0]};
                    const v2f x1 = (v2f){R0[cc1], R0[cc1]};
                    a0 = __builtin_elementwise_fma(x0, Wsel[kc], a0);
                    a1 = __builtin_elementwise_fma(x1, Wsel[kc], a1);
                }
                {
                    const v2f x0 = (v2f){R1[cc0], R1[cc0]};
                    const v2f x1 = (v2f){R1[cc1], R1[cc1]};
                    a0 = __builtin_elementwise_fma(x0, Wsel[3 + kc], a0);
                    a1 = __builtin_elementwise_fma(x1, Wsel[3 + kc], a1);
                }
                {
                    const v2f x0 = (v2f){R2[cc0], R2[cc0]};
                    const v2f x1 = (v2f){R2[cc1], R2[cc1]};
                    a0 = __builtin_elementwise_fma(x0, Wsel[6 + kc], a0);
                    a1 = __builtin_elementwise_fma(x1, Wsel[6 + kc], a1);
                }
            }
            // 2x2 maxpool: dc-merge packed, then cross-q via DPP
            const v2f m = __builtin_elementwise_max(a0, a1);
            const float Px = fmaxf(m.x, dpp_swap1_f(m.x));
            const float Py = fmaxf(m.y, dpp_swap1_f(m.y));
            // partner filter pair's pooled values via cross-h DPP
            const float Qx = dpp_swap2_f(Px);
            const float Qy = dpp_swap2_f(Py);
            // deconv: this lane's single tap kl = 2q+h
            float z = Db;
            z = fmaf(Px, Ds0, z);
            z = fmaf(Py, Ds1, z);
            z = fmaf(Qx, Ds2, z);
            z = fmaf(Qy, Ds3, z);

            // log-pairing: one log per z-pair product
            const int pos = i * 5 + j;     // compile-time after unroll
            if (pos == 24) {
                sb ^= __float_as_uint(z);
                l2 += __log2f(fabsf(z));
            } else if (pos & 1) {
                const float zp = zpend * z;
                sb ^= __float_as_uint(zp);
                l2 += __log2f(fabsf(zp));
            } else {
                zpend = z;
            }
        }
    }

    // quad combine: each lane contributed 25 of the sample's 100 z's
    l2 += dpp_swap1_f(l2);
    l2 += dpp_swap2_f(l2);
    sb ^= dpp_swap1_u(sb);
    sb ^= dpp_swap2_u(sb);

    const int s = blockIdx.x * 32 + w * 16 + g;
    const int r = lane & 3;
    if (r == 0)      out[s]     = (sb & 0x80000000u) ? -1.0f : 1.0f;
    else if (r == 1) out[B + s] = l2 * 0.69314718055994531f;
}

extern "C" void kernel_launch(void* const* d_in, const int* in_sizes, int n_in,
                              void* d_out, int out_size, void* d_ws, size_t ws_size,
                              hipStream_t stream) {
    const float* v  = (const float*)d_in[0];
    const float* cw = (const float*)d_in[1];
    const float* cb = (const float*)d_in[2];
    const float* dw = (const float*)d_in[3];
    const float* db = (const float*)d_in[4];
    float* out = (float*)d_out;

    const int B = in_sizes[0] / 100;       // 262144
    const int grid = B / 32;               // 32 samples per 2-wave block
    CNN2D_37495064494620_kernel<<<grid, 128, 0, stream>>>(v, cw, cb, dw, db, out, B);
}

// Round 4
// 170.902 us; speedup vs baseline: 1.0915x; 1.0915x over previous
//
#include <hip/hip_runtime.h>
#include <math.h>

// v10: v9 structure, spill fixed (launch_bounds 128,4 -> VGPR cap 128).
//
// Post-mortem v9: __launch_bounds__(128,6) squeezed allocator to 40 VGPR ->
// row cache + conv state spilled to scratch: WRITE_SIZE 112.7MB (expected
// 2.1MB), FETCH 80MB, kernel 68.9us memory-bound on spill traffic.
// Occupancy lever itself worked (21->51%); it was masked by spills.
// Changes vs v9:
//  (1) __launch_bounds__(128, 4): VGPR cap 128, body wants ~80-100 -> no
//      spill; LDS (12.8KB/block) still caps at 12 blocks/CU = 24 waves/CU.
//  (2) everything else identical: 16 samples/wave, rolling row cache
//      (55 ds_read_b64/batch), static ds offsets, stage-first weight overlap,
//      log-pairing, quad DPP combine.

typedef float v2f __attribute__((ext_vector_type(2)));

#define SREAD(x) __int_as_float(__builtin_amdgcn_readfirstlane(__float_as_int(x)))
#define WAITVM(N) asm volatile("s_waitcnt vmcnt(" #N ")" ::: "memory")

__device__ __forceinline__ float dpp_swap1_f(float x) {      // lane ^ 1
    return __int_as_float(__builtin_amdgcn_mov_dpp(__float_as_int(x), 0xB1, 0xF, 0xF, true));
}
__device__ __forceinline__ float dpp_swap2_f(float x) {      // lane ^ 2
    return __int_as_float(__builtin_amdgcn_mov_dpp(__float_as_int(x), 0x4E, 0xF, 0xF, true));
}
__device__ __forceinline__ unsigned dpp_swap1_u(unsigned x) {
    return (unsigned)__builtin_amdgcn_mov_dpp((int)x, 0xB1, 0xF, 0xF, true);
}
__device__ __forceinline__ unsigned dpp_swap2_u(unsigned x) {
    return (unsigned)__builtin_amdgcn_mov_dpp((int)x, 0x4E, 0xF, 0xF, true);
}

__device__ __forceinline__ void gload16(const float* g, float* l) {
    __builtin_amdgcn_global_load_lds(
        (const __attribute__((address_space(1))) void*)g,
        (__attribute__((address_space(3))) void*)l, 16, 0, 0);
}
__device__ __forceinline__ void gload4(const float* g, float* l) {
    __builtin_amdgcn_global_load_lds(
        (const __attribute__((address_space(1))) void*)g,
        (__attribute__((address_space(3))) void*)l, 4, 0, 0);
}

__global__ __launch_bounds__(128, 4) void CNN2D_37495064494620_kernel(
    const float* __restrict__ v,
    const float* __restrict__ cw,   // [4,1,3,3]
    const float* __restrict__ cb,   // [4]
    const float* __restrict__ dw,   // [4,1,2,2]
    const float* __restrict__ db,   // [1]
    float* __restrict__ out,        // [2*B]
    int B)
{
    const int lane = threadIdx.x & 63;
    const int w    = threadIdx.x >> 6;    // wave in block (0..1)
    const int q    = lane & 1;            // conv-row parity
    const int h    = (lane >> 1) & 1;     // filter-pair owner (f0,f1 | f2,f3)
    const int g    = lane >> 2;           // sample within wave (0..15)

    __shared__ __align__(16) float smraw[3200];   // 2 waves x 16 samples x 100
    float* sm = smraw + w * 1600;

    // ---- stage FIRST: this wave's 16 samples (6400B = 6x1024B + 256B) ----
    const float* gb = v + (size_t)(blockIdx.x * 2 + w) * 1600;
    #pragma unroll
    for (int k = 0; k < 6; ++k)
        gload16(gb + k * 256 + lane * 4, sm + k * 256);
    gload4(gb + 1536 + lane, sm + 1536);

    // ---- uniform weights -> SGPRs (s_loads overlap the VMEM flight) ----
    float Wf[4][9];
    #pragma unroll
    for (int f = 0; f < 4; ++f)
        #pragma unroll
        for (int t = 0; t < 9; ++t)
            Wf[f][t] = SREAD(cw[f * 9 + t]);
    v2f Wsel[9];
    #pragma unroll
    for (int t = 0; t < 9; ++t)
        Wsel[t] = (v2f){ h ? Wf[2][t] : Wf[0][t], h ? Wf[3][t] : Wf[1][t] };
    const float cb0 = SREAD(cb[0]), cb1 = SREAD(cb[1]);
    const float cb2 = SREAD(cb[2]), cb3 = SREAD(cb[3]);
    const v2f Cbsel = (v2f){ h ? cb2 : cb0, h ? cb3 : cb1 };

    float Dw4[4][4];
    #pragma unroll
    for (int f = 0; f < 4; ++f)
        #pragma unroll
        for (int t = 0; t < 4; ++t)
            Dw4[f][t] = SREAD(dw[f * 4 + t]);
    const float Db = SREAD(db[0]);
    float Dkl[4];                         // this lane's tap kl = 2q+h
    #pragma unroll
    for (int f = 0; f < 4; ++f) {
        const float e01 = h ? Dw4[f][1] : Dw4[f][0];
        const float e23 = h ? Dw4[f][3] : Dw4[f][2];
        Dkl[f] = q ? e23 : e01;
    }
    const float Ds0 = h ? Dkl[2] : Dkl[0];   // own filter pair first
    const float Ds1 = h ? Dkl[3] : Dkl[1];
    const float Ds2 = h ? Dkl[0] : Dkl[2];
    const float Ds3 = h ? Dkl[1] : Dkl[3];

    WAITVM(0);   // this wave's 7 staging loads landed

    // Row bases: all reads below are static offsets from these two regs.
    const float* my  = sm + g * 100;
    const float* myq = my + q * 10;          // row (0+q): center rows = myq+20i
    const float* mx  = my + (q ? 0 : 90);    // wrap row: r0(0) and rowC(i=4)

    auto load5 = [&](float* dst, const float* src) {
        #pragma unroll
        for (int t = 0; t < 5; ++t) {
            float2 x = *(const float2*)(src + 2 * t);
            dst[2 * t] = x.x; dst[2 * t + 1] = x.y;
        }
    };

    unsigned sb = 0u;       // XOR of z sign bits (this lane's 25 taps)
    float l2 = 0.0f;        // sum of log2|z|
    float zpend = 0.0f;     // pending z for log-pairing

    float X[2][10];         // rotating parity-(1-q) rows: X[i&1]=r0(i)
    float RB[10];           // center row r1(i)
    load5(X[0], mx);        // r0(0)

    #pragma unroll
    for (int i = 0; i < 5; ++i) {
        load5(RB, myq + 20 * i);                              // r1 = 2i+q
        load5(X[(i + 1) & 1], (i == 4) ? mx : (myq + 10 + 20 * i));  // r2
        const float* R0 = X[i & 1];
        const float* R1 = RB;
        const float* R2 = X[(i + 1) & 1];

        #pragma unroll
        for (int j = 0; j < 5; ++j) {
            v2f a0 = Cbsel, a1 = Cbsel;     // cols 2j, 2j+1; this lane's 2 filters
            #pragma unroll
            for (int kc = 0; kc < 3; ++kc) {
                const int cc0 = (2 * j + kc + 9) % 10;        // compile-time
                const int cc1 = (2 * j + 1 + kc + 9) % 10;
                {
                    const v2f x0 = (v2f){R0[cc0], R0[cc0]};
                    const v2f x1 = (v2f){R0[cc1], R0[cc1]};
                    a0 = __builtin_elementwise_fma(x0, Wsel[kc], a0);
                    a1 = __builtin_elementwise_fma(x1, Wsel[kc], a1);
                }
                {
                    const v2f x0 = (v2f){R1[cc0], R1[cc0]};
                    const v2f x1 = (v2f){R1[cc1], R1[cc1]};
                    a0 = __builtin_elementwise_fma(x0, Wsel[3 + kc], a0);
                    a1 = __builtin_elementwise_fma(x1, Wsel[3 + kc], a1);
                }
                {
                    const v2f x0 = (v2f){R2[cc0], R2[cc0]};
                    const v2f x1 = (v2f){R2[cc1], R2[cc1]};
                    a0 = __builtin_elementwise_fma(x0, Wsel[6 + kc], a0);
                    a1 = __builtin_elementwise_fma(x1, Wsel[6 + kc], a1);
                }
            }
            // 2x2 maxpool: dc-merge packed, then cross-q via DPP
            const v2f m = __builtin_elementwise_max(a0, a1);
            const float Px = fmaxf(m.x, dpp_swap1_f(m.x));
            const float Py = fmaxf(m.y, dpp_swap1_f(m.y));
            // partner filter pair's pooled values via cross-h DPP
            const float Qx = dpp_swap2_f(Px);
            const float Qy = dpp_swap2_f(Py);
            // deconv: this lane's single tap kl = 2q+h
            float z = Db;
            z = fmaf(Px, Ds0, z);
            z = fmaf(Py, Ds1, z);
            z = fmaf(Qx, Ds2, z);
            z = fmaf(Qy, Ds3, z);

            // log-pairing: one log per z-pair product
            const int pos = i * 5 + j;     // compile-time after unroll
            if (pos == 24) {
                sb ^= __float_as_uint(z);
                l2 += __log2f(fabsf(z));
            } else if (pos & 1) {
                const float zp = zpend * z;
                sb ^= __float_as_uint(zp);
                l2 += __log2f(fabsf(zp));
            } else {
                zpend = z;
            }
        }
    }

    // quad combine: each lane contributed 25 of the sample's 100 z's
    l2 += dpp_swap1_f(l2);
    l2 += dpp_swap2_f(l2);
    sb ^= dpp_swap1_u(sb);
    sb ^= dpp_swap2_u(sb);

    const int s = blockIdx.x * 32 + w * 16 + g;
    const int r = lane & 3;
    if (r == 0)      out[s]     = (sb & 0x80000000u) ? -1.0f : 1.0f;
    else if (r == 1) out[B + s] = l2 * 0.69314718055994531f;
}

extern "C" void kernel_launch(void* const* d_in, const int* in_sizes, int n_in,
                              void* d_out, int out_size, void* d_ws, size_t ws_size,
                              hipStream_t stream) {
    const float* v  = (const float*)d_in[0];
    const float* cw = (const float*)d_in[1];
    const float* cb = (const float*)d_in[2];
    const float* dw = (const float*)d_in[3];
    const float* db = (const float*)d_in[4];
    float* out = (float*)d_out;

    const int B = in_sizes[0] / 100;       // 262144
    const int grid = B / 32;               // 32 samples per 2-wave block
    CNN2D_37495064494620_kernel<<<grid, 128, 0, stream>>>(v, cw, cb, dw, db, out, B);
}

// Round 5
// 170.753 us; speedup vs baseline: 1.0924x; 1.0009x over previous
//
#include <hip/hip_runtime.h>
#include <math.h>

// v11: column-packed conv -- pk_fma operands are natural register pairs.
//
// Post-mortem v10: occupancy 12->16-20 waves/CU changed nothing (48us kernel)
// -> not latency-bound; VALU issue volume is the limiter. Measured chip VALU
// ~26us vs ~11us hand-count: the gap is operand-build v_movs. v10 packed over
// FILTERS, so every pk_fma input was a loop-variant scalar broadcast
// (v2f){R[cc],R[cc]} -> compiler materializes an aligned VGPR pair per use
// (~500+ movs/batch). Changes vs v10:
//  (1) pack over output COLUMN pairs: a_f = {conv_f[2j], conv_f[2j+1]}.
//      Taps need column pairs (2j-1,2j)/(2j,2j+1)/(2j+1,2j+2) = even pairs
//      A[k] (direct from ds_read_b64), odd pairs Bp[k] + wrap pair (built
//      ONCE per row, 5 copies), weights = loop-invariant broadcast pairs
//      (built once, 18 pairs). Zero per-j operand builds.
//  (2) dc-merge becomes scalar fmaxf(a.x,a.y); rest of tail unchanged.
//  (3) __launch_bounds__(128,3): VGPR cap ~168 for ~115 live -> no spill.

typedef float v2f __attribute__((ext_vector_type(2)));

#define SREAD(x) __int_as_float(__builtin_amdgcn_readfirstlane(__float_as_int(x)))
#define WAITVM(N) asm volatile("s_waitcnt vmcnt(" #N ")" ::: "memory")

__device__ __forceinline__ float dpp_swap1_f(float x) {      // lane ^ 1
    return __int_as_float(__builtin_amdgcn_mov_dpp(__float_as_int(x), 0xB1, 0xF, 0xF, true));
}
__device__ __forceinline__ float dpp_swap2_f(float x) {      // lane ^ 2
    return __int_as_float(__builtin_amdgcn_mov_dpp(__float_as_int(x), 0x4E, 0xF, 0xF, true));
}
__device__ __forceinline__ unsigned dpp_swap1_u(unsigned x) {
    return (unsigned)__builtin_amdgcn_mov_dpp((int)x, 0xB1, 0xF, 0xF, true);
}
__device__ __forceinline__ unsigned dpp_swap2_u(unsigned x) {
    return (unsigned)__builtin_amdgcn_mov_dpp((int)x, 0x4E, 0xF, 0xF, true);
}

__device__ __forceinline__ void gload16(const float* g, float* l) {
    __builtin_amdgcn_global_load_lds(
        (const __attribute__((address_space(1))) void*)g,
        (__attribute__((address_space(3))) void*)l, 16, 0, 0);
}
__device__ __forceinline__ void gload4(const float* g, float* l) {
    __builtin_amdgcn_global_load_lds(
        (const __attribute__((address_space(1))) void*)g,
        (__attribute__((address_space(3))) void*)l, 4, 0, 0);
}

// One 10-wide row, extended to all column pairs needed by the conv:
//   a[k] = {x[2k],   x[2k+1]}   (direct ds_read_b64)
//   b[k] = {x[2k+1], x[2k+2]}   (one cross-half copy each)
//   wr   = {x[9],    x[0]}      (wrap pair)
struct RowP { v2f a[5]; v2f b[4]; v2f wr; };

__global__ __launch_bounds__(128, 3) void CNN2D_37495064494620_kernel(
    const float* __restrict__ v,
    const float* __restrict__ cw,   // [4,1,3,3]
    const float* __restrict__ cb,   // [4]
    const float* __restrict__ dw,   // [4,1,2,2]
    const float* __restrict__ db,   // [1]
    float* __restrict__ out,        // [2*B]
    int B)
{
    const int lane = threadIdx.x & 63;
    const int w    = threadIdx.x >> 6;    // wave in block (0..1)
    const int q    = lane & 1;            // conv-row parity
    const int h    = (lane >> 1) & 1;     // filter-pair owner (f0,f1 | f2,f3)
    const int g    = lane >> 2;           // sample within wave (0..15)

    __shared__ __align__(16) float smraw[3200];   // 2 waves x 16 samples x 100
    float* sm = smraw + w * 1600;

    // ---- stage FIRST: this wave's 16 samples (6400B = 6x1024B + 256B) ----
    const float* gb = v + (size_t)(blockIdx.x * 2 + w) * 1600;
    #pragma unroll
    for (int k = 0; k < 6; ++k)
        gload16(gb + k * 256 + lane * 4, sm + k * 256);
    gload4(gb + 1536 + lane, sm + 1536);

    // ---- uniform weights (s_loads overlap the VMEM flight) ----
    float Wf[4][9];
    #pragma unroll
    for (int f = 0; f < 4; ++f)
        #pragma unroll
        for (int t = 0; t < 9; ++t)
            Wf[f][t] = SREAD(cw[f * 9 + t]);
    // loop-invariant broadcast pairs for this lane's two filters (2h, 2h+1)
    v2f Wp0[9], Wp1[9];
    #pragma unroll
    for (int t = 0; t < 9; ++t) {
        const float w0 = h ? Wf[2][t] : Wf[0][t];
        const float w1 = h ? Wf[3][t] : Wf[1][t];
        Wp0[t] = (v2f){w0, w0};
        Wp1[t] = (v2f){w1, w1};
    }
    const float cb0 = SREAD(cb[0]), cb1 = SREAD(cb[1]);
    const float cb2 = SREAD(cb[2]), cb3 = SREAD(cb[3]);
    const float cbe0 = h ? cb2 : cb0;
    const float cbe1 = h ? cb3 : cb1;
    const v2f Cb0p = (v2f){cbe0, cbe0};
    const v2f Cb1p = (v2f){cbe1, cbe1};

    float Dw4[4][4];
    #pragma unroll
    for (int f = 0; f < 4; ++f)
        #pragma unroll
        for (int t = 0; t < 4; ++t)
            Dw4[f][t] = SREAD(dw[f * 4 + t]);
    const float Db = SREAD(db[0]);
    float Dkl[4];                         // this lane's tap kl = 2q+h
    #pragma unroll
    for (int f = 0; f < 4; ++f) {
        const float e01 = h ? Dw4[f][1] : Dw4[f][0];
        const float e23 = h ? Dw4[f][3] : Dw4[f][2];
        Dkl[f] = q ? e23 : e01;
    }
    const float Ds0 = h ? Dkl[2] : Dkl[0];   // own filter pair first
    const float Ds1 = h ? Dkl[3] : Dkl[1];
    const float Ds2 = h ? Dkl[0] : Dkl[2];
    const float Ds3 = h ? Dkl[1] : Dkl[3];

    WAITVM(0);   // this wave's 7 staging loads landed

    // Row bases: static offsets from these two pointers.
    const float* my  = sm + g * 100;
    const float* myq = my + q * 10;          // center rows: myq + 20*i
    const float* mx  = my + (q ? 0 : 90);    // wrap row (r0(0) and r2(4))

    auto loadrow = [&](RowP& r, const float* src) {
        #pragma unroll
        for (int t = 0; t < 5; ++t) {
            float2 x = *(const float2*)(src + 2 * t);
            r.a[t] = (v2f){x.x, x.y};
        }
        #pragma unroll
        for (int t = 0; t < 4; ++t)
            r.b[t] = (v2f){r.a[t].y, r.a[t + 1].x};
        r.wr = (v2f){r.a[4].y, r.a[0].x};
    };

    // tap operand for output-col pair (2j,2j+1), kernel col kc (compile-time)
    auto tap = [&](const RowP& r, int kc, int j) -> v2f {
        if (kc == 1) return r.a[j];                       // (2j,   2j+1)
        if (kc == 0) return (j == 0) ? r.wr : r.b[j - 1]; // (2j-1, 2j)
        return (j == 4) ? r.wr : r.b[j];                  // (2j+1, 2j+2)
    };

    unsigned sb = 0u;       // XOR of z sign bits (this lane's 25 taps)
    float l2 = 0.0f;        // sum of log2|z|
    float zpend = 0.0f;     // pending z for log-pairing

    RowP X0, X1, C;         // X* rotate the shared parity-(1-q) rows
    loadrow(X0, mx);        // r0(0)

    #pragma unroll
    for (int i = 0; i < 5; ++i) {
        RowP& R0r = (i & 1) ? X1 : X0;     // r0(i) (already loaded)
        RowP& R2r = (i & 1) ? X0 : X1;     // r2(i) (load now; becomes r0(i+1))
        loadrow(C, myq + 20 * i);                              // center r1
        loadrow(R2r, (i == 4) ? mx : (myq + 10 + 20 * i));     // r2

        #pragma unroll
        for (int j = 0; j < 5; ++j) {
            v2f a0 = Cb0p, a1 = Cb1p;      // {conv[2j], conv[2j+1]} per filter
            #pragma unroll
            for (int kr = 0; kr < 3; ++kr) {
                const RowP& r = (kr == 0) ? R0r : ((kr == 1) ? C : R2r);
                #pragma unroll
                for (int kc = 0; kc < 3; ++kc) {
                    const v2f x = tap(r, kc, j);
                    a0 = __builtin_elementwise_fma(x, Wp0[kr * 3 + kc], a0);
                    a1 = __builtin_elementwise_fma(x, Wp1[kr * 3 + kc], a1);
                }
            }
            // 2x2 maxpool: column merge scalar, then cross-q via DPP
            const float m0v = fmaxf(a0.x, a0.y);
            const float m1v = fmaxf(a1.x, a1.y);
            const float Px = fmaxf(m0v, dpp_swap1_f(m0v));
            const float Py = fmaxf(m1v, dpp_swap1_f(m1v));
            // partner filter pair's pooled values via cross-h DPP
            const float Qx = dpp_swap2_f(Px);
            const float Qy = dpp_swap2_f(Py);
            // deconv: this lane's single tap kl = 2q+h
            float z = Db;
            z = fmaf(Px, Ds0, z);
            z = fmaf(Py, Ds1, z);
            z = fmaf(Qx, Ds2, z);
            z = fmaf(Qy, Ds3, z);

            // log-pairing: one log per z-pair product
            const int pos = i * 5 + j;     // compile-time after unroll
            if (pos == 24) {
                sb ^= __float_as_uint(z);
                l2 += __log2f(fabsf(z));
            } else if (pos & 1) {
                const float zp = zpend * z;
                sb ^= __float_as_uint(zp);
                l2 += __log2f(fabsf(zp));
            } else {
                zpend = z;
            }
        }
    }

    // quad combine: each lane contributed 25 of the sample's 100 z's
    l2 += dpp_swap1_f(l2);
    l2 += dpp_swap2_f(l2);
    sb ^= dpp_swap1_u(sb);
    sb ^= dpp_swap2_u(sb);

    const int s = blockIdx.x * 32 + w * 16 + g;
    const int r = lane & 3;
    if (r == 0)      out[s]     = (sb & 0x80000000u) ? -1.0f : 1.0f;
    else if (r == 1) out[B + s] = l2 * 0.69314718055994531f;
}

extern "C" void kernel_launch(void* const* d_in, const int* in_sizes, int n_in,
                              void* d_out, int out_size, void* d_ws, size_t ws_size,
                              hipStream_t stream) {
    const float* v  = (const float*)d_in[0];
    const float* cw = (const float*)d_in[1];
    const float* cb = (const float*)d_in[2];
    const float* dw = (const float*)d_in[3];
    const float* db = (const float*)d_in[4];
    float* out = (float*)d_out;

    const int B = in_sizes[0] / 100;       // 262144
    const int grid = B / 32;               // 32 samples per 2-wave block
    CNN2D_37495064494620_kernel<<<grid, 128, 0, stream>>>(v, cw, cb, dw, db, out, B);
}